// Round 17
// baseline (85.619 us; speedup 1.0000x reference)
//
#include <hip/hip_runtime.h>

typedef unsigned short ushort_t;
typedef __bf16 bf16_8 __attribute__((ext_vector_type(8)));
typedef float f32x4 __attribute__((ext_vector_type(4)));

#define VOCAB 4101
#define KPAD  4224   // 33 * 128
#define NROWS 3072   // 1024 * 3
#define HDIM  768
#define ODIM  256

// ---- helpers -------------------------------------------------------------

static __device__ __forceinline__ unsigned short f2bf(float f) {
  unsigned int u = __float_as_uint(f);
  unsigned int r = (u + 0x7fffu + ((u >> 16) & 1u)) >> 16;
  return (unsigned short)r;
}

static __device__ __forceinline__ void async_copy16(const void* g, void* l) {
  __builtin_amdgcn_global_load_lds(
      (const __attribute__((address_space(1))) void*)g,
      (__attribute__((address_space(3))) void*)l, 16, 0, 0);
}

// ---- fused prep kernel (R15-proven, 256 thr): hist + weight transposes ---

__global__ __launch_bounds__(256)
void prep_kernel(const int* __restrict__ X,
                 const float* __restrict__ W1,
                 const float* __restrict__ W2,
                 ushort_t* __restrict__ A,
                 ushort_t* __restrict__ W1T,
                 ushort_t* __restrict__ W2T,
                 float* __restrict__ scales) {
  __shared__ __align__(16) unsigned char smem[16896];
  const int bid = blockIdx.x;

  if (bid < NROWS) {
    unsigned int* h = (unsigned int*)smem;
    const int r = bid;
    uint4* h4 = (uint4*)smem;
    for (int i = threadIdx.x; i < 1056; i += 256)
      h4[i] = (uint4){0u, 0u, 0u, 0u};
    __syncthreads();

    const int4* xp = reinterpret_cast<const int4*>(X + (size_t)r * 4096);
    #pragma unroll
    for (int i = 0; i < 4; ++i) {
      int4 v = xp[i * 256 + threadIdx.x];
      atomicAdd(&h[v.x], 1u);
      atomicAdd(&h[v.y], 1u);
      atomicAdd(&h[v.z], 1u);
      atomicAdd(&h[v.w], 1u);
    }
    __syncthreads();

    const unsigned int ignored = h[0] + h[1] + h[2] + h[3] + h[4];
    const float s = 10.0f / (float)(4096u - ignored);
    if (threadIdx.x == 0) scales[r] = s;

    uint4* Ar4 = (uint4*)(A + (size_t)r * KPAD);
    for (int i = threadIdx.x; i < 528; i += 256) {
      const int b0 = i * 8;
      unsigned int w[4];
      #pragma unroll
      for (int j = 0; j < 4; ++j) {
        int ia = b0 + 2 * j, ib = b0 + 2 * j + 1;
        unsigned int ca = (ia >= 5 && ia < VOCAB) ? h[ia] : 0u;
        unsigned int cb = (ib >= 5 && ib < VOCAB) ? h[ib] : 0u;
        w[j] = (unsigned int)f2bf((float)ca) | ((unsigned int)f2bf((float)cb) << 16);
      }
      Ar4[i] = (uint4){w[0], w[1], w[2], w[3]};
    }
  } else {
    ushort_t (*tile)[65] = (ushort_t(*)[65])smem;
    const float* src; ushort_t* dst;
    int K, N, Kpad, kb, nb;
    if (bid < NROWS + 792) {
      const int t = bid - NROWS;           // tp1: 66 x 12 tiles
      src = W1; dst = W1T; K = VOCAB; N = HDIM; Kpad = KPAD;
      kb = (t % 66) * 64; nb = (t / 66) * 64;
    } else {
      const int t = bid - NROWS - 792;     // tp2: 12 x 4 tiles
      src = W2; dst = W2T; K = HDIM; N = ODIM; Kpad = HDIM;
      kb = (t % 12) * 64; nb = (t / 12) * 64;
    }
    const int tr = threadIdx.x >> 6;
    const int tc = threadIdx.x & 63;
    #pragma unroll
    for (int i = 0; i < 16; ++i) {
      int r = i * 4 + tr;
      int k = kb + r;
      float v = (k < K) ? src[(size_t)k * N + nb + tc] : 0.0f;
      tile[r][tc] = f2bf(v);
    }
    __syncthreads();
    #pragma unroll
    for (int i = 0; i < 16; ++i) {
      int r = i * 4 + tr;
      dst[(size_t)(nb + r) * Kpad + kb + tc] = tile[tc][r];
    }
  }
}

// ---- GEMM1: BM=BN=128, BK=128, grid 24x6 = 144 blocks (all concurrent) ---
// Fill-bound analysis: 96^2 tile fills 48KB per 1.18M MACs (41 B/M-MAC);
// 128^2 fills 64KB per 2.1M (31 B/M-MAC, -25% L2->LDS traffic).
// 256 thr = 4 waves (2m x 2n); wave-tile 64x64 = acc[4][4] of 16x16
// (0.5 ds_reads/MFMA vs 0.67 at 48x48).  LDS 2x(32+32)KB = 128KB, 1 blk/CU.
// Same-m blocks share one XCD (flat = x + 24y, 24%8=0) -> A panels fill
// exactly one L2 each.  Split-half LDS (two [128][64] halves, 128B row
// stride: R8-proven 0-conflict pattern) + T2 XOR swizzle both-sides.
// 2-phase dbuf (R8/R10-proven; deep pipelines refuted twice R6/R9).

__global__ __launch_bounds__(256)
void gemm1_fused(const ushort_t* __restrict__ A, int lda,
                 const ushort_t* __restrict__ Bt, int ldb,
                 int ktiles,
                 const float* __restrict__ scales,
                 const float* __restrict__ bias,
                 ushort_t* __restrict__ H) {
  __shared__ __align__(16) ushort_t Alds[2][2 * 128 * 64];   // 2 x 32 KB
  __shared__ __align__(16) ushort_t Blds[2][2 * 128 * 64];   // 2 x 32 KB
  const int tid  = threadIdx.x;
  const int lane = tid & 63;
  const int wv   = tid >> 6;      // 0..3
  const int wrow = wv >> 1;       // 0..1  -> 64 rows each
  const int wcol = wv & 1;        // 0..1  -> 64 cols each
  const int m0   = blockIdx.x * 128;
  const int n0   = blockIdx.y * 128;

  f32x4 acc[4][4];
  #pragma unroll
  for (int m = 0; m < 4; ++m)
    #pragma unroll
    for (int n = 0; n < 4; ++n)
      acc[m][n] = (f32x4){0.f, 0.f, 0.f, 0.f};

  // Tile: 2048 16B-chunks (1024 per [128][64] half); 256 thr -> 8 iters.
  // cd = i*256+tid; hf = cd>>10; rem = cd&1023; row = rem>>3; c8 = rem&7.
#define STAGE(bi, kt)                                                          \
  {                                                                            \
    const int k0_ = (kt) * 128;                                                \
    _Pragma("unroll")                                                          \
    for (int i = 0; i < 8; ++i) {                                              \
      const int cd  = i * 256 + tid;                                           \
      const int hf  = cd >> 10;                                                \
      const int rem = cd & 1023;                                               \
      const int row = rem >> 3;                                                \
      const int cc  = (rem & 7) ^ (row & 7);                                   \
      async_copy16(A + (size_t)(m0 + row) * lda + k0_ + hf * 64 + cc * 8,      \
                   (char*)&Alds[bi][0] + cd * 16);                             \
    }                                                                          \
    _Pragma("unroll")                                                          \
    for (int i = 0; i < 8; ++i) {                                              \
      const int cd  = i * 256 + tid;                                           \
      const int hf  = cd >> 10;                                                \
      const int rem = cd & 1023;                                               \
      const int row = rem >> 3;                                                \
      const int cc  = (rem & 7) ^ (row & 7);                                   \
      async_copy16(Bt + (size_t)(n0 + row) * ldb + k0_ + hf * 64 + cc * 8,     \
                   (char*)&Blds[bi][0] + cd * 16);                             \
    }                                                                          \
  }

  STAGE(0, 0);
  __syncthreads();

  int cur = 0;
  for (int t = 0; t < ktiles; ++t) {
    if (t + 1 < ktiles) STAGE(cur ^ 1, t + 1);
    const int hi = lane >> 4;                  // 0..3
    #pragma unroll
    for (int kk = 0; kk < 4; ++kk) {
      const int hf  = kk >> 1;
      const int ca8 = (kk & 1) * 4 + hi;       // chunk col within half, 0..7
      bf16_8 af[4], bf[4];
      #pragma unroll
      for (int m = 0; m < 4; ++m) {
        const int ra = wrow * 64 + m * 16 + (lane & 15);
        af[m] = *(const bf16_8*)((const char*)&Alds[cur][0] +
                                 (hf * 1024 + ra * 8 + (ca8 ^ (ra & 7))) * 16);
      }
      #pragma unroll
      for (int n = 0; n < 4; ++n) {
        const int rb = wcol * 64 + n * 16 + (lane & 15);
        bf[n] = *(const bf16_8*)((const char*)&Blds[cur][0] +
                                 (hf * 1024 + rb * 8 + (ca8 ^ (rb & 7))) * 16);
      }
      #pragma unroll
      for (int m = 0; m < 4; ++m)
        #pragma unroll
        for (int n = 0; n < 4; ++n)
          acc[m][n] = __builtin_amdgcn_mfma_f32_16x16x32_bf16(af[m], bf[n],
                                                              acc[m][n], 0, 0, 0);
    }
    __syncthreads();
    cur ^= 1;
  }
#undef STAGE

  // D col = lane&15, row = 4*(lane>>4)+reg
  const int rbase = (lane >> 4) * 4;
  const int cf    = lane & 15;
  #pragma unroll
  for (int m = 0; m < 4; ++m) {
    #pragma unroll
    for (int n = 0; n < 4; ++n) {
      #pragma unroll
      for (int reg = 0; reg < 4; ++reg) {
        const int gr = m0 + wrow * 64 + m * 16 + rbase + reg;
        const int gc = n0 + wcol * 64 + n * 16 + cf;
        float v = fmaxf(acc[m][n][reg] * scales[gr] + bias[gc], 0.0f);
        H[(size_t)gr * HDIM + gc] = f2bf(v);
      }
    }
  }
}

// ---- GEMM2: BM=96, BN=32, BK=128, grid 32x8 = 256 blocks (R15 body) ------

__global__ __launch_bounds__(384)
void gemm2_fused(const ushort_t* __restrict__ A, int lda,
                 const ushort_t* __restrict__ Bt, int ldb,
                 int ktiles,
                 const float* __restrict__ bias,
                 float* __restrict__ outp) {
  __shared__ __align__(16) ushort_t Alds[2][2 * 96 * 64];   // 2 x 24 KB
  __shared__ __align__(16) ushort_t Blds[2][2 * 32 * 64];   // 2 x  8 KB
  const int tid  = threadIdx.x;
  const int lane = tid & 63;
  const int wv   = tid >> 6;      // 0..5 -> 16 rows each
  const int m0   = blockIdx.x * 96;
  const int n0   = blockIdx.y * 32;

  f32x4 acc[2];
  acc[0] = (f32x4){0.f, 0.f, 0.f, 0.f};
  acc[1] = (f32x4){0.f, 0.f, 0.f, 0.f};

#define STAGE(bi, kt)                                                          \
  {                                                                            \
    const int k0_ = (kt) * 128;                                                \
    _Pragma("unroll")                                                          \
    for (int i = 0; i < 4; ++i) {                                              \
      const int cd  = i * 384 + tid;                                           \
      const int hf  = (i >= 2) ? 1 : 0;                                        \
      const int rem = cd - hf * 768;                                           \
      const int row = rem >> 3;                                                \
      const int cc  = (rem & 7) ^ (row & 7);                                   \
      async_copy16(A + (size_t)(m0 + row) * lda + k0_ + hf * 64 + cc * 8,      \
                   (char*)&Alds[bi][0] + cd * 16);                             \
    }                                                                          \
    {                                                                          \
      const int cd  = tid;                                                     \
      const int hf  = cd >> 8;                                                 \
      const int rem = cd & 255;                                                \
      const int row = rem >> 3;                                                \
      const int cc  = (rem & 7) ^ (row & 7);                                   \
      async_copy16(Bt + (size_t)(n0 + row) * ldb + k0_ + hf * 64 + cc * 8,     \
                   (char*)&Blds[bi][0] + cd * 16);                             \
    }                                                                          \
    if (tid < 128) {                                                           \
      const int cd  = 384 + tid;                                               \
      const int rem = cd & 255;                                                \
      const int row = rem >> 3;                                                \
      const int cc  = (rem & 7) ^ (row & 7);                                   \
      async_copy16(Bt + (size_t)(n0 + row) * ldb + k0_ + 64 + cc * 8,          \
                   (char*)&Blds[bi][0] + cd * 16);                             \
    }                                                                          \
  }

  STAGE(0, 0);
  __syncthreads();

  int cur = 0;
  for (int t = 0; t < ktiles; ++t) {
    if (t + 1 < ktiles) STAGE(cur ^ 1, t + 1);
    const int hi = lane >> 4;
    #pragma unroll
    for (int kk = 0; kk < 4; ++kk) {
      const int hf  = kk >> 1;
      const int ca8 = (kk & 1) * 4 + hi;
      bf16_8 af, bf[2];
      {
        const int ra = wv * 16 + (lane & 15);
        af = *(const bf16_8*)((const char*)&Alds[cur][0] +
                              (hf * 768 + ra * 8 + (ca8 ^ (ra & 7))) * 16);
      }
      #pragma unroll
      for (int n = 0; n < 2; ++n) {
        const int rb = n * 16 + (lane & 15);
        bf[n] = *(const bf16_8*)((const char*)&Blds[cur][0] +
                                 (hf * 256 + rb * 8 + (ca8 ^ (rb & 7))) * 16);
      }
      #pragma unroll
      for (int n = 0; n < 2; ++n)
        acc[n] = __builtin_amdgcn_mfma_f32_16x16x32_bf16(af, bf[n], acc[n], 0, 0, 0);
    }
    __syncthreads();
    cur ^= 1;
  }
#undef STAGE

  const int rbase = (lane >> 4) * 4;
  const int cf    = lane & 15;
  #pragma unroll
  for (int n = 0; n < 2; ++n) {
    #pragma unroll
    for (int reg = 0; reg < 4; ++reg) {
      const int gr = m0 + wv * 16 + rbase + reg;
      const int gc = n0 + n * 16 + cf;
      float v = acc[n][reg] + bias[gc];
      outp[(size_t)(gr % 3) * (1024 * ODIM) + (size_t)(gr / 3) * ODIM + gc] = v;
    }
  }
}

// ---- launch --------------------------------------------------------------

extern "C" void kernel_launch(void* const* d_in, const int* in_sizes, int n_in,
                              void* d_out, int out_size, void* d_ws, size_t ws_size,
                              hipStream_t stream) {
  const int*   X  = (const int*)d_in[0];
  const float* W1 = (const float*)d_in[1];
  const float* b1 = (const float*)d_in[2];
  const float* W2 = (const float*)d_in[3];
  const float* b2 = (const float*)d_in[4];
  float* out = (float*)d_out;

  char* ws = (char*)d_ws;
  ushort_t* A      = (ushort_t*)(ws);                  // 3072*4224*2 = 25,952,256 B
  ushort_t* W1T    = (ushort_t*)(ws + 25952256);       //  768*4224*2 =  6,488,064 B
  ushort_t* H      = (ushort_t*)(ws + 32440320);       // 3072*768*2  =  4,718,592 B
  ushort_t* W2T    = (ushort_t*)(ws + 37158912);       //  256*768*2  =    393,216 B
  float*    scales = (float*)   (ws + 37552128);       //     12,288 B

  // prep: 3072 hist blocks + 792 W1-transpose tiles + 48 W2-transpose tiles
  prep_kernel<<<NROWS + 792 + 48, 256, 0, stream>>>(X, W1, W2, A, W1T, W2T, scales);

  // GEMM1: M=3072 N=768 K=4224 (33 tiles of 128); grid 24x6 = 144 blocks
  gemm1_fused<<<dim3(NROWS / 128, HDIM / 128), 256, 0, stream>>>(
      A, KPAD, W1T, KPAD, KPAD / 128, scales, b1, H);

  // GEMM2: M=3072 N=256 K=768 (6 tiles of 128); grid 32x8 = 256 blocks
  gemm2_fused<<<dim3(NROWS / 96, ODIM / 32), 384, 0, stream>>>(
      H, HDIM, W2T, HDIM, HDIM / 128, b2, out);
}

// Round 18
// 63.133 us; speedup vs baseline: 1.3562x; 1.3562x over previous
//
#include <hip/hip_runtime.h>

typedef unsigned short ushort_t;
typedef __bf16 bf16_8 __attribute__((ext_vector_type(8)));
typedef float f32x4 __attribute__((ext_vector_type(4)));

#define VOCAB 4101
#define KPAD  4224   // 33 * 128
#define NROWS 3072   // 1024 * 3
#define HDIM  768
#define ODIM  256

// ---- helpers -------------------------------------------------------------

static __device__ __forceinline__ unsigned short f2bf(float f) {
  unsigned int u = __float_as_uint(f);
  unsigned int r = (u + 0x7fffu + ((u >> 16) & 1u)) >> 16;
  return (unsigned short)r;
}

static __device__ __forceinline__ void async_copy16(const void* g, void* l) {
  __builtin_amdgcn_global_load_lds(
      (const __attribute__((address_space(1))) void*)g,
      (__attribute__((address_space(3))) void*)l, 16, 0, 0);
}

// ---- fused prep kernel: histogram + both weight transposes ---------------
// Block roles by flat blockIdx.x:
//   [0, 3072)           : per-row histogram -> bf16 counts A + scales
//   [3072, 3072+792)    : W1 [4101][768] -> W1T [768][4224] bf16 (66x12 tiles)
//   [3864, 3864+48)     : W2 [768][256]  -> W2T [256][768]  bf16 (12x4 tiles)

__global__ __launch_bounds__(256)
void prep_kernel(const int* __restrict__ X,
                 const float* __restrict__ W1,
                 const float* __restrict__ W2,
                 ushort_t* __restrict__ A,
                 ushort_t* __restrict__ W1T,
                 ushort_t* __restrict__ W2T,
                 float* __restrict__ scales) {
  __shared__ __align__(16) unsigned char smem[16896];
  const int bid = blockIdx.x;

  if (bid < NROWS) {
    // ---------------- histogram role ----------------
    unsigned int* h = (unsigned int*)smem;
    const int r = bid;
    for (int i = threadIdx.x; i < KPAD; i += 256) h[i] = 0u;
    __syncthreads();

    const int4* xp = reinterpret_cast<const int4*>(X + (size_t)r * 4096);
    #pragma unroll
    for (int i = 0; i < 4; ++i) {
      int4 v = xp[i * 256 + threadIdx.x];
      atomicAdd(&h[v.x], 1u);
      atomicAdd(&h[v.y], 1u);
      atomicAdd(&h[v.z], 1u);
      atomicAdd(&h[v.w], 1u);
    }
    __syncthreads();

    const unsigned int ignored = h[0] + h[1] + h[2] + h[3] + h[4];
    const float s = 10.0f / (float)(4096u - ignored);
    if (threadIdx.x == 0) scales[r] = s;

    unsigned int* Ar = (unsigned int*)(A + (size_t)r * KPAD);
    for (int i = threadIdx.x; i < KPAD / 2; i += 256) {
      int i0 = 2 * i, i1 = 2 * i + 1;
      unsigned int c0 = (i0 >= 5 && i0 < VOCAB) ? h[i0] : 0u;
      unsigned int c1 = (i1 >= 5 && i1 < VOCAB) ? h[i1] : 0u;
      Ar[i] = (unsigned int)f2bf((float)c0) | ((unsigned int)f2bf((float)c1) << 16);
    }
  } else {
    // ---------------- transpose roles ----------------
    ushort_t (*tile)[65] = (ushort_t(*)[65])smem;
    const float* src; ushort_t* dst;
    int K, N, Kpad, kb, nb;
    if (bid < NROWS + 792) {
      const int t = bid - NROWS;           // tp1: 66 x 12 tiles
      src = W1; dst = W1T; K = VOCAB; N = HDIM; Kpad = KPAD;
      kb = (t % 66) * 64; nb = (t / 66) * 64;
    } else {
      const int t = bid - NROWS - 792;     // tp2: 12 x 4 tiles
      src = W2; dst = W2T; K = HDIM; N = ODIM; Kpad = HDIM;
      kb = (t % 12) * 64; nb = (t / 12) * 64;
    }
    const int tr = threadIdx.x >> 6;
    const int tc = threadIdx.x & 63;
    #pragma unroll
    for (int i = 0; i < 16; ++i) {
      int r = i * 4 + tr;
      int k = kb + r;
      float v = (k < K) ? src[(size_t)k * N + nb + tc] : 0.0f;
      tile[r][tc] = f2bf(v);
    }
    __syncthreads();
    #pragma unroll
    for (int i = 0; i < 16; ++i) {
      int r = i * 4 + tr;
      dst[(size_t)(nb + r) * Kpad + kb + tc] = tile[tc][r];
    }
  }
}

// ---- GEMM1: BM=BN=96, BK=128, grid 32x8 = 256 blocks (exactly 1/CU) ------
// C[M][N] = A[M][K] * Bt[N][K]^T, fused scale+bias+relu -> bf16 H.
// 256 thr = 4 waves (2m x 2n); wave-tile 48x48 = acc[3][3] of 16x16.
// R8-proven 2-phase dbuf; T2 XOR swizzle (linear gload_lds dest, inverse-
// swizzled global src chunk cc = c ^ (row&7), same XOR on ds_read).
// Measured session best: total 63.2us (R11).

__global__ __launch_bounds__(256)
void gemm1_fused(const ushort_t* __restrict__ A, int lda,
                 const ushort_t* __restrict__ Bt, int ldb,
                 int ktiles,
                 const float* __restrict__ scales,
                 const float* __restrict__ bias,
                 ushort_t* __restrict__ H) {
  __shared__ __align__(16) ushort_t Alds[2][96 * 128];   // 2 x 24 KB
  __shared__ __align__(16) ushort_t Blds[2][96 * 128];   // 2 x 24 KB
  const int tid  = threadIdx.x;
  const int lane = tid & 63;
  const int wv   = tid >> 6;      // 0..3
  const int wrow = wv >> 1;       // 0..1  -> 48 rows each
  const int wcol = wv & 1;        // 0..1  -> 48 cols each
  const int m0   = blockIdx.x * 96;
  const int n0   = blockIdx.y * 96;

  f32x4 acc[3][3];
  #pragma unroll
  for (int m = 0; m < 3; ++m)
    #pragma unroll
    for (int n = 0; n < 3; ++n)
      acc[m][n] = (f32x4){0.f, 0.f, 0.f, 0.f};

  // A tile: 96 rows x 16 chunks = 1536 chunks; 256 thr -> 6 each. Same B.
#define STAGE(bi, kt)                                                          \
  {                                                                            \
    const int k0_ = (kt) * 128;                                                \
    _Pragma("unroll")                                                          \
    for (int i = 0; i < 6; ++i) {                                              \
      const int cd  = i * 256 + tid;                                           \
      const int row = cd >> 4;                                                 \
      const int cc  = (cd & 15) ^ (row & 7);                                   \
      async_copy16(A + (size_t)(m0 + row) * lda + k0_ + cc * 8,                \
                   (char*)&Alds[bi][0] + cd * 16);                             \
    }                                                                          \
    _Pragma("unroll")                                                          \
    for (int i = 0; i < 6; ++i) {                                              \
      const int cd  = i * 256 + tid;                                           \
      const int row = cd >> 4;                                                 \
      const int cc  = (cd & 15) ^ (row & 7);                                   \
      async_copy16(Bt + (size_t)(n0 + row) * ldb + k0_ + cc * 8,               \
                   (char*)&Blds[bi][0] + cd * 16);                             \
    }                                                                          \
  }

  STAGE(0, 0);
  __syncthreads();

  int cur = 0;
  for (int t = 0; t < ktiles; ++t) {
    if (t + 1 < ktiles) STAGE(cur ^ 1, t + 1);
    const int hi = lane >> 4;                  // 0..3
    #pragma unroll
    for (int kk = 0; kk < 4; ++kk) {
      bf16_8 af[3], bf[3];
      #pragma unroll
      for (int m = 0; m < 3; ++m) {
        const int ra = wrow * 48 + m * 16 + (lane & 15);
        const int ca = kk * 4 + hi;            // chunk col 0..15
        af[m] = *(const bf16_8*)((const char*)&Alds[cur][0] +
                                 (ra * 16 + (ca ^ (ra & 7))) * 16);
      }
      #pragma unroll
      for (int n = 0; n < 3; ++n) {
        const int rb = wcol * 48 + n * 16 + (lane & 15);
        const int cb = kk * 4 + hi;
        bf[n] = *(const bf16_8*)((const char*)&Blds[cur][0] +
                                 (rb * 16 + (cb ^ (rb & 7))) * 16);
      }
      #pragma unroll
      for (int m = 0; m < 3; ++m)
        #pragma unroll
        for (int n = 0; n < 3; ++n)
          acc[m][n] = __builtin_amdgcn_mfma_f32_16x16x32_bf16(af[m], bf[n],
                                                              acc[m][n], 0, 0, 0);
    }
    __syncthreads();
    cur ^= 1;
  }
#undef STAGE

  // D col = lane&15, row = 4*(lane>>4)+reg
  const int rbase = (lane >> 4) * 4;
  const int cf    = lane & 15;
  #pragma unroll
  for (int m = 0; m < 3; ++m) {
    #pragma unroll
    for (int n = 0; n < 3; ++n) {
      #pragma unroll
      for (int reg = 0; reg < 4; ++reg) {
        const int gr = m0 + wrow * 48 + m * 16 + rbase + reg;
        const int gc = n0 + wcol * 48 + n * 16 + cf;
        float v = fmaxf(acc[m][n][reg] * scales[gr] + bias[gc], 0.0f);
        H[(size_t)gr * HDIM + gc] = f2bf(v);
      }
    }
  }
}

// ---- GEMM2: BM=96, BN=32, BK=128, grid 32x8 = 256 blocks (R10-proven) ----
// 384 thr = 6 waves (6m x 1n); wave-tile 16x32 = acc[1][2]; 6 K-tiles.
// out[(row%3)*262144 + (row/3)*256 + col] = acc + bias[col]

__global__ __launch_bounds__(384)
void gemm2_fused(const ushort_t* __restrict__ A, int lda,
                 const ushort_t* __restrict__ Bt, int ldb,
                 int ktiles,
                 const float* __restrict__ bias,
                 float* __restrict__ outp) {
  __shared__ __align__(16) ushort_t Alds[2][96 * 128];   // 2 x 24 KB
  __shared__ __align__(16) ushort_t Blds[2][32 * 128];   // 2 x  8 KB
  const int tid  = threadIdx.x;
  const int lane = tid & 63;
  const int wv   = tid >> 6;      // 0..5 -> 16 rows each
  const int m0   = blockIdx.x * 96;
  const int n0   = blockIdx.y * 32;

  f32x4 acc[2];
  acc[0] = (f32x4){0.f, 0.f, 0.f, 0.f};
  acc[1] = (f32x4){0.f, 0.f, 0.f, 0.f};

#define STAGE(bi, kt)                                                          \
  {                                                                            \
    const int k0_ = (kt) * 128;                                                \
    _Pragma("unroll")                                                          \
    for (int i = 0; i < 4; ++i) {                                              \
      const int cd  = i * 384 + tid;                                           \
      const int row = cd >> 4;                                                 \
      const int cc  = (cd & 15) ^ (row & 7);                                   \
      async_copy16(A + (size_t)(m0 + row) * lda + k0_ + cc * 8,                \
                   (char*)&Alds[bi][0] + cd * 16);                             \
    }                                                                          \
    {                                                                          \
      const int cd  = tid;                                                     \
      const int row = cd >> 4;                                                 \
      const int cc  = (cd & 15) ^ (row & 7);                                   \
      async_copy16(Bt + (size_t)(n0 + row) * ldb + k0_ + cc * 8,               \
                   (char*)&Blds[bi][0] + cd * 16);                             \
    }                                                                          \
    if (tid < 128) {                                                           \
      const int cd  = 384 + tid;                                               \
      const int row = cd >> 4;                                                 \
      const int cc  = (cd & 15) ^ (row & 7);                                   \
      async_copy16(Bt + (size_t)(n0 + row) * ldb + k0_ + cc * 8,               \
                   (char*)&Blds[bi][0] + cd * 16);                             \
    }                                                                          \
  }

  STAGE(0, 0);
  __syncthreads();

  int cur = 0;
  for (int t = 0; t < ktiles; ++t) {
    if (t + 1 < ktiles) STAGE(cur ^ 1, t + 1);
    const int hi = lane >> 4;
    #pragma unroll
    for (int kk = 0; kk < 4; ++kk) {
      bf16_8 af, bf[2];
      {
        const int ra = wv * 16 + (lane & 15);
        const int ca = kk * 4 + hi;
        af = *(const bf16_8*)((const char*)&Alds[cur][0] +
                              (ra * 16 + (ca ^ (ra & 7))) * 16);
      }
      #pragma unroll
      for (int n = 0; n < 2; ++n) {
        const int rb = n * 16 + (lane & 15);
        const int cb = kk * 4 + hi;
        bf[n] = *(const bf16_8*)((const char*)&Blds[cur][0] +
                                 (rb * 16 + (cb ^ (rb & 7))) * 16);
      }
      #pragma unroll
      for (int n = 0; n < 2; ++n)
        acc[n] = __builtin_amdgcn_mfma_f32_16x16x32_bf16(af, bf[n], acc[n], 0, 0, 0);
    }
    __syncthreads();
    cur ^= 1;
  }
#undef STAGE

  const int rbase = (lane >> 4) * 4;
  const int cf    = lane & 15;
  #pragma unroll
  for (int n = 0; n < 2; ++n) {
    #pragma unroll
    for (int reg = 0; reg < 4; ++reg) {
      const int gr = m0 + wv * 16 + rbase + reg;
      const int gc = n0 + n * 16 + cf;
      float v = acc[n][reg] + bias[gc];
      outp[(size_t)(gr % 3) * (1024 * ODIM) + (size_t)(gr / 3) * ODIM + gc] = v;
    }
  }
}

// ---- launch --------------------------------------------------------------

extern "C" void kernel_launch(void* const* d_in, const int* in_sizes, int n_in,
                              void* d_out, int out_size, void* d_ws, size_t ws_size,
                              hipStream_t stream) {
  const int*   X  = (const int*)d_in[0];
  const float* W1 = (const float*)d_in[1];
  const float* b1 = (const float*)d_in[2];
  const float* W2 = (const float*)d_in[3];
  const float* b2 = (const float*)d_in[4];
  float* out = (float*)d_out;

  char* ws = (char*)d_ws;
  ushort_t* A      = (ushort_t*)(ws);                  // 3072*4224*2 = 25,952,256 B
  ushort_t* W1T    = (ushort_t*)(ws + 25952256);       //  768*4224*2 =  6,488,064 B
  ushort_t* H      = (ushort_t*)(ws + 32440320);       // 3072*768*2  =  4,718,592 B
  ushort_t* W2T    = (ushort_t*)(ws + 37158912);       //  256*768*2  =    393,216 B
  float*    scales = (float*)   (ws + 37552128);       //     12,288 B

  // prep: 3072 hist blocks + 792 W1-transpose tiles + 48 W2-transpose tiles
  prep_kernel<<<NROWS + 792 + 48, 256, 0, stream>>>(X, W1, W2, A, W1T, W2T, scales);

  // GEMM1: M=3072 N=768 K=4224 (33 tiles of 128); grid 32x8 = 256 blocks
  gemm1_fused<<<dim3(NROWS / 96, HDIM / 96), 256, 0, stream>>>(
      A, KPAD, W1T, KPAD, KPAD / 128, scales, b1, H);

  // GEMM2: M=3072 N=256 K=768 (6 tiles of 128); grid 32x8 = 256 blocks
  gemm2_fused<<<dim3(NROWS / 96, ODIM / 32), 384, 0, stream>>>(
      H, HDIM, W2T, HDIM, HDIM / 128, b2, out);
}